// Round 5
// baseline (94.972 us; speedup 1.0000x reference)
//
#include <hip/hip_runtime.h>
#include <hip/hip_bf16.h>

// NT-Xent loss, N=4096, Z=128, T=0.5.
//
// Round 4 established: scratch matrix stored in MFMA-FRAGMENT ORDER so every
// A/B fragment load is a coalesced global_load_dwordx4 (1 KB/wave-load).
//   pack[(G*4 + ks)*64 + q*16 + n] (16B granules) = rows G*16+n,
//   k in [ks*32+q*8, +8).
// Round 5: sim matrix is SYMMETRIC -> compute only tiles ct>=rt. Off-diagonal
// 128x128 blocks credit row-sums to denom[rows] AND col-sums to denom[cols]
// (E_ij = E_ji); diagonal blocks compute full tile, mask self-diag, row-sums
// only. Halves MFMA + exp2 work, ~40% less VMEM.
//
//  k_normalize: row-normalize z1/z2 (fp32), quantize to bf16 scaled by
//               QS = sqrt(2*log2(e)) (folds 1/T=2 and exp->exp2), write in
//               fragment order; exact fp32 pair-cosines pos[4096]; zero denom.
//  k_simsum:    denom[i] = sum_{j!=i} exp(2*sim_ij), upper-triangle blocks.
//               No LDS, no barriers; ~115 unified regs -> 4 waves/SIMD
//               (round 2 lesson: never force min-waves near the reg budget).
//  k_finish:    out = (sum_i log denom_i - 4 * sum_p pos_p) / 8192

#define N_PAIRS 4096
#define ZDIM    128
#define NROWS   8192
#define QS 1.6986437717f   // sqrt(2 * log2(e))

typedef __bf16 bf16x8 __attribute__((ext_vector_type(8)));
typedef float  floatx4 __attribute__((ext_vector_type(4)));

__global__ __launch_bounds__(256) void k_normalize(
    const float* __restrict__ z1, const float* __restrict__ z2,
    __hip_bfloat16* __restrict__ pack, float* __restrict__ pos,
    float* __restrict__ denom)
{
    const int zi = blockIdx.x * 256 + threadIdx.x;   // grid 1024 blocks; 32 zero denom
    if (zi < NROWS) denom[zi] = 0.0f;

    const int w = threadIdx.x >> 6;
    const int lane = threadIdx.x & 63;
    const int p = blockIdx.x * 4 + w;            // pair index, < 4096
    const float2 a = ((const float2*)(z1 + (size_t)p * ZDIM))[lane];
    const float2 b = ((const float2*)(z2 + (size_t)p * ZDIM))[lane];
    float s1 = a.x * a.x + a.y * a.y;
    float s2 = b.x * b.x + b.y * b.y;
    float d  = a.x * b.x + a.y * b.y;
    #pragma unroll
    for (int off = 1; off < 64; off <<= 1) {
        s1 += __shfl_xor(s1, off, 64);
        s2 += __shfl_xor(s2, off, 64);
        d  += __shfl_xor(d,  off, 64);
    }
    const float n1 = fmaxf(sqrtf(s1), 1e-8f);
    const float n2 = fmaxf(sqrtf(s2), 1e-8f);
    const float i1 = 1.0f / n1, i2 = 1.0f / n2;
    const float q1 = i1 * QS, q2 = i2 * QS;
    float2 na; na.x = a.x * q1; na.y = a.y * q1;
    float2 nb; nb.x = b.x * q2; nb.y = b.y * q2;

    // lane holds elements e0=2*lane, e0+1 of its row:
    //   ks = lane>>4 ; q = (lane>>2)&3 ; j = (lane&3)*2
    // pack elem idx for row r: ((r>>4)*4 + ks)*512 + q*128 + (r&15)*8 + j
    const int ks = lane >> 4;
    const int qq = (lane >> 2) & 3;
    const int jj = (lane & 3) * 2;
    const int r1 = p, r2 = p + N_PAIRS;
    const size_t i1e = ((size_t)((r1 >> 4) * 4 + ks)) * 512 + qq * 128 + (r1 & 15) * 8 + jj;
    const size_t i2e = ((size_t)((r2 >> 4) * 4 + ks)) * 512 + qq * 128 + (r2 & 15) * 8 + jj;
    *(__hip_bfloat162*)(pack + i1e) = __float22bfloat162_rn(na);
    *(__hip_bfloat162*)(pack + i2e) = __float22bfloat162_rn(nb);
    if (lane == 0) pos[p] = d * i1 * i2;
}

// Block: 256 thr = 4 waves stacked vertically; wave w owns rows
// [rt*128 + w*32, +32). Block tile 128x128, 2 col-steps of 64; all waves
// share each step's 16 KB of B-frags (dedup in L1). grid 64x64, blocks with
// ct<rt exit immediately (2080 live blocks).
__global__ __launch_bounds__(256) void k_simsum(
    const __hip_bfloat16* __restrict__ pack, float* __restrict__ denom)
{
    const int rt = blockIdx.x;          // row tile [0,64)
    const int ct = blockIdx.y;          // col tile [0,64)
    if (ct < rt) return;                // upper triangle only
    const bool diag = (rt == ct);

    const int tid  = threadIdx.x;
    const int lane = tid & 63;
    const int w    = tid >> 6;
    const int q    = lane >> 4;         // quad 0..3
    const int l16  = lane & 15;

    // ---- persistent A fragments: wave's 32 rows x full K=128 (32 VGPRs) ----
    const int rowb = rt * 128 + w * 32;
    const __hip_bfloat16* Abase =
        pack + ((size_t)(rowb >> 4) * 4) * 512 + lane * 8;
    bf16x8 afrag[2][4];
    #pragma unroll
    for (int mt = 0; mt < 2; ++mt)
        #pragma unroll
        for (int ks = 0; ks < 4; ++ks)
            afrag[mt][ks] = *(const bf16x8*)(Abase + mt * 2048 + ks * 512);

    float rowsum[2][4];
    float colsum[2][4];                 // [it][nt], lane-local partial
    #pragma unroll
    for (int a = 0; a < 2; ++a)
        #pragma unroll
        for (int b = 0; b < 4; ++b) { rowsum[a][b] = 0.0f; colsum[a][b] = 0.0f; }

    #pragma unroll
    for (int it = 0; it < 2; ++it) {
        floatx4 acc[2][4];
        #pragma unroll
        for (int mt = 0; mt < 2; ++mt)
            #pragma unroll
            for (int nt = 0; nt < 4; ++nt) {
                acc[mt][nt].x = 0.f; acc[mt][nt].y = 0.f;
                acc[mt][nt].z = 0.f; acc[mt][nt].w = 0.f;
            }
        const int colb = ct * 128 + it * 64;
        const __hip_bfloat16* Bbase =
            pack + ((size_t)(colb >> 4) * 4) * 512 + lane * 8;
        bf16x8 bfrag[4][4];   // [nt][ks] — load all first, max outstanding VMEM
        #pragma unroll
        for (int nt = 0; nt < 4; ++nt)
            #pragma unroll
            for (int ks = 0; ks < 4; ++ks)
                bfrag[nt][ks] = *(const bf16x8*)(Bbase + nt * 2048 + ks * 512);
        #pragma unroll
        for (int ks = 0; ks < 4; ++ks)
            #pragma unroll
            for (int mt = 0; mt < 2; ++mt)
                #pragma unroll
                for (int nt = 0; nt < 4; ++nt)
                    acc[mt][nt] = __builtin_amdgcn_mfma_f32_16x16x32_bf16(
                        afrag[mt][ks], bfrag[nt][ks], acc[mt][nt], 0, 0, 0);

        // ---- fused epilogue. C/D layout: col = l16, row = q*4 + r ----
        if (diag) {
            // full tile, self-diagonal masked, row-sums only
            #pragma unroll
            for (int mt = 0; mt < 2; ++mt) {
                const int rowtb = w * 32 + mt * 16;      // relative to block
                #pragma unroll
                for (int nt = 0; nt < 4; ++nt) {
                    const int coltb = it * 64 + nt * 16;
                    if (rowtb == coltb) {
                        #pragma unroll
                        for (int r = 0; r < 4; ++r) {
                            const float e = __builtin_amdgcn_exp2f(acc[mt][nt][r]);
                            rowsum[mt][r] += (l16 == q * 4 + r) ? 0.0f : e;
                        }
                    } else {
                        #pragma unroll
                        for (int r = 0; r < 4; ++r)
                            rowsum[mt][r] += __builtin_amdgcn_exp2f(acc[mt][nt][r]);
                    }
                }
            }
        } else {
            // off-diagonal: row-sums AND col-sums (symmetry credit)
            #pragma unroll
            for (int mt = 0; mt < 2; ++mt)
                #pragma unroll
                for (int nt = 0; nt < 4; ++nt)
                    #pragma unroll
                    for (int r = 0; r < 4; ++r) {
                        const float e = __builtin_amdgcn_exp2f(acc[mt][nt][r]);
                        rowsum[mt][r] += e;
                        colsum[it][nt] += e;
                    }
        }
    }

    // ---- row-sum reduction: across the 16 lanes holding the same row ----
    #pragma unroll
    for (int mt = 0; mt < 2; ++mt)
        #pragma unroll
        for (int r = 0; r < 4; ++r) {
            float s = rowsum[mt][r];
            s += __shfl_xor(s, 1, 64);
            s += __shfl_xor(s, 2, 64);
            s += __shfl_xor(s, 4, 64);
            s += __shfl_xor(s, 8, 64);
            rowsum[mt][r] = s;
        }
    if (l16 == 0) {
        #pragma unroll
        for (int mt = 0; mt < 2; ++mt)
            #pragma unroll
            for (int r = 0; r < 4; ++r) {
                const int grow = rowb + mt * 16 + q * 4 + r;
                atomicAdd(&denom[grow], rowsum[mt][r]);
            }
    }
    // ---- col-sum reduction: lane-local already has sum over its 8 rows;
    //      fold across quads (rows), then one coalesced atomic per tile ----
    if (!diag) {
        #pragma unroll
        for (int it = 0; it < 2; ++it)
            #pragma unroll
            for (int nt = 0; nt < 4; ++nt) {
                float s = colsum[it][nt];
                s += __shfl_xor(s, 16, 64);
                s += __shfl_xor(s, 32, 64);
                if (q == 0)
                    atomicAdd(&denom[ct * 128 + it * 64 + nt * 16 + l16], s);
            }
    }
}

__global__ __launch_bounds__(1024) void k_finish(
    const float* __restrict__ denom, const float* __restrict__ pos,
    float* __restrict__ out)
{
    __shared__ float red[16];
    const int t = threadIdx.x;
    const int lane = t & 63, wv = t >> 6;
    float s = 0.0f;
    for (int i = t; i < NROWS; i += 1024) s += __logf(denom[i]);
    float p = 0.0f;
    for (int i = t; i < N_PAIRS; i += 1024) p += pos[i];
    float v = s - 4.0f * p;   // sum_i pos_i/T over 2N rows = 4 * sum_p cos_p
    #pragma unroll
    for (int off = 1; off < 64; off <<= 1) v += __shfl_xor(v, off, 64);
    if (lane == 0) red[wv] = v;
    __syncthreads();
    if (wv == 0) {
        float x = (lane < 16) ? red[lane] : 0.0f;
        #pragma unroll
        for (int off = 1; off < 16; off <<= 1) x += __shfl_xor(x, off, 64);
        if (lane == 0) out[0] = x / (float)NROWS;
    }
}

extern "C" void kernel_launch(void* const* d_in, const int* in_sizes, int n_in,
                              void* d_out, int out_size, void* d_ws, size_t ws_size,
                              hipStream_t stream) {
    const float* z1 = (const float*)d_in[0];
    const float* z2 = (const float*)d_in[1];
    float* out = (float*)d_out;

    char* ws = (char*)d_ws;
    __hip_bfloat16* pack = (__hip_bfloat16*)ws;                // 2 MB
    float* denom = (float*)(ws + (size_t)NROWS * ZDIM * 2);    // 32 KB
    float* pos   = denom + NROWS;                              // 16 KB

    k_normalize<<<N_PAIRS / 4, 256, 0, stream>>>(z1, z2, pack, pos, denom);
    k_simsum<<<dim3(64, 64), 256, 0, stream>>>(pack, denom);
    k_finish<<<1, 1024, 0, stream>>>(denom, pos, out);
}

// Round 6
// 90.656 us; speedup vs baseline: 1.0476x; 1.0476x over previous
//
#include <hip/hip_runtime.h>
#include <hip/hip_bf16.h>

// NT-Xent loss, N=4096, Z=128, T=0.5.
//
// Round 4: scratch matrix in MFMA-FRAGMENT ORDER -> every A/B fragment load
// is a coalesced global_load_dwordx4 (1 KB/wave-load).
//   pack[(G*4 + ks)*64 + q*16 + n] (16B granules) = rows G*16+n,
//   k in [ks*32+q*8, +8).
// Round 5: symmetry (E_ij = E_ji): only tiles ct>=rt; off-diag blocks credit
// row-sums AND col-sums. Regressed: dead-block imbalance (64x64 grid, 2016
// early-exits) + colsum regs tipping the 128-reg/4-wave boundary.
// Round 6: compact 1D triangular grid (exactly 2080 blocks, sqrt decode);
// colsum folded per col-step (4 regs, atomic inside loop); B-frag loads
// issued ks-major so the first MFMA waits on 4 loads, not 16.
//
//  k_normalize: row-normalize (fp32), quantize bf16 scaled by
//               QS = sqrt(2*log2(e)) (folds 1/T=2 and exp->exp2), write in
//               fragment order; exact fp32 pair-cosines pos[4096]; zero denom.
//  k_simsum:    denom[i] = sum_{j!=i} exp(2*sim_ij), upper-triangle blocks.
//               No LDS, no barriers; ~115 live regs -> 4 waves/SIMD natural.
//  k_finish:    out = (sum_i log denom_i - 4 * sum_p pos_p) / 8192

#define N_PAIRS 4096
#define ZDIM    128
#define NROWS   8192
#define QS 1.6986437717f   // sqrt(2 * log2(e))
#define NT64 64            // 64 row/col tiles of 128
#define NBLK 2080          // 64*65/2 upper-triangle blocks

typedef __bf16 bf16x8 __attribute__((ext_vector_type(8)));
typedef float  floatx4 __attribute__((ext_vector_type(4)));

__global__ __launch_bounds__(256) void k_normalize(
    const float* __restrict__ z1, const float* __restrict__ z2,
    __hip_bfloat16* __restrict__ pack, float* __restrict__ pos,
    float* __restrict__ denom)
{
    const int zi = blockIdx.x * 256 + threadIdx.x;   // grid 1024 blocks; 32 zero denom
    if (zi < NROWS) denom[zi] = 0.0f;

    const int w = threadIdx.x >> 6;
    const int lane = threadIdx.x & 63;
    const int p = blockIdx.x * 4 + w;            // pair index, < 4096
    const float2 a = ((const float2*)(z1 + (size_t)p * ZDIM))[lane];
    const float2 b = ((const float2*)(z2 + (size_t)p * ZDIM))[lane];
    float s1 = a.x * a.x + a.y * a.y;
    float s2 = b.x * b.x + b.y * b.y;
    float d  = a.x * b.x + a.y * b.y;
    #pragma unroll
    for (int off = 1; off < 64; off <<= 1) {
        s1 += __shfl_xor(s1, off, 64);
        s2 += __shfl_xor(s2, off, 64);
        d  += __shfl_xor(d,  off, 64);
    }
    const float n1 = fmaxf(sqrtf(s1), 1e-8f);
    const float n2 = fmaxf(sqrtf(s2), 1e-8f);
    const float i1 = 1.0f / n1, i2 = 1.0f / n2;
    const float q1 = i1 * QS, q2 = i2 * QS;
    float2 na; na.x = a.x * q1; na.y = a.y * q1;
    float2 nb; nb.x = b.x * q2; nb.y = b.y * q2;

    // lane holds elements e0=2*lane, e0+1 of its row:
    //   ks = lane>>4 ; q = (lane>>2)&3 ; j = (lane&3)*2
    // pack elem idx for row r: ((r>>4)*4 + ks)*512 + q*128 + (r&15)*8 + j
    const int ks = lane >> 4;
    const int qq = (lane >> 2) & 3;
    const int jj = (lane & 3) * 2;
    const int r1 = p, r2 = p + N_PAIRS;
    const size_t i1e = ((size_t)((r1 >> 4) * 4 + ks)) * 512 + qq * 128 + (r1 & 15) * 8 + jj;
    const size_t i2e = ((size_t)((r2 >> 4) * 4 + ks)) * 512 + qq * 128 + (r2 & 15) * 8 + jj;
    *(__hip_bfloat162*)(pack + i1e) = __float22bfloat162_rn(na);
    *(__hip_bfloat162*)(pack + i2e) = __float22bfloat162_rn(nb);
    if (lane == 0) pos[p] = d * i1 * i2;
}

// Block: 256 thr = 4 waves stacked vertically; wave w owns rows
// [rt*128 + w*32, +32). Block tile 128x128, 2 col-steps of 64; all waves
// share each step's 16 KB of B-frags (dedup in L1). Grid: exactly NBLK
// upper-triangle blocks, decoded from the linear index.
__global__ __launch_bounds__(256) void k_simsum(
    const __hip_bfloat16* __restrict__ pack, float* __restrict__ denom)
{
    // ---- triangular decode: L -> (rt, ct), ct >= rt (wave-uniform SALU) ----
    // T(r) = #blocks in rows < r = r*(129-r)/2 ; rt = max r with T(r) <= L
    const int L = blockIdx.x;
    int rt = (int)((129.0f - sqrtf(16641.0f - 8.0f * (float)L)) * 0.5f);
    while (rt * (129 - rt) / 2 > L) --rt;                 // fp-rounding guards
    while ((rt + 1) * (128 - rt) / 2 <= L) ++rt;
    const int ct = rt + (L - rt * (129 - rt) / 2);
    const bool diag = (rt == ct);

    const int tid  = threadIdx.x;
    const int lane = tid & 63;
    const int w    = tid >> 6;
    const int q    = lane >> 4;         // quad 0..3
    const int l16  = lane & 15;

    // ---- persistent A fragments: wave's 32 rows x full K=128 (32 VGPRs) ----
    const int rowb = rt * 128 + w * 32;
    const __hip_bfloat16* Abase =
        pack + ((size_t)(rowb >> 4) * 4) * 512 + lane * 8;
    bf16x8 afrag[2][4];
    #pragma unroll
    for (int mt = 0; mt < 2; ++mt)
        #pragma unroll
        for (int ks = 0; ks < 4; ++ks)
            afrag[mt][ks] = *(const bf16x8*)(Abase + mt * 2048 + ks * 512);

    float rowsum[2][4];
    #pragma unroll
    for (int mt = 0; mt < 2; ++mt)
        #pragma unroll
        for (int r = 0; r < 4; ++r) rowsum[mt][r] = 0.0f;

    #pragma unroll
    for (int it = 0; it < 2; ++it) {
        floatx4 acc[2][4];
        #pragma unroll
        for (int mt = 0; mt < 2; ++mt)
            #pragma unroll
            for (int nt = 0; nt < 4; ++nt) {
                acc[mt][nt].x = 0.f; acc[mt][nt].y = 0.f;
                acc[mt][nt].z = 0.f; acc[mt][nt].w = 0.f;
            }
        const int colb = ct * 128 + it * 64;
        const __hip_bfloat16* Bbase =
            pack + ((size_t)(colb >> 4) * 4) * 512 + lane * 8;
        // B-frag loads ks-MAJOR: first MFMA group needs only loads 0..3,
        // leaving 12 still in flight behind it.
        bf16x8 bfrag[4][4];   // [ks][nt]
        #pragma unroll
        for (int ks = 0; ks < 4; ++ks)
            #pragma unroll
            for (int nt = 0; nt < 4; ++nt)
                bfrag[ks][nt] = *(const bf16x8*)(Bbase + nt * 2048 + ks * 512);
        #pragma unroll
        for (int ks = 0; ks < 4; ++ks)
            #pragma unroll
            for (int mt = 0; mt < 2; ++mt)
                #pragma unroll
                for (int nt = 0; nt < 4; ++nt)
                    acc[mt][nt] = __builtin_amdgcn_mfma_f32_16x16x32_bf16(
                        afrag[mt][ks], bfrag[ks][nt], acc[mt][nt], 0, 0, 0);

        // ---- fused epilogue. C/D layout: col = l16, row = q*4 + r ----
        if (diag) {
            // full tile, self-diagonal masked, row-sums only
            #pragma unroll
            for (int mt = 0; mt < 2; ++mt) {
                const int rowtb = w * 32 + mt * 16;      // relative to block
                #pragma unroll
                for (int nt = 0; nt < 4; ++nt) {
                    const int coltb = it * 64 + nt * 16;
                    if (rowtb == coltb) {
                        #pragma unroll
                        for (int r = 0; r < 4; ++r) {
                            const float e = __builtin_amdgcn_exp2f(acc[mt][nt][r]);
                            rowsum[mt][r] += (l16 == q * 4 + r) ? 0.0f : e;
                        }
                    } else {
                        #pragma unroll
                        for (int r = 0; r < 4; ++r)
                            rowsum[mt][r] += __builtin_amdgcn_exp2f(acc[mt][nt][r]);
                    }
                }
            }
        } else {
            // off-diagonal: row-sums AND col-sums (symmetry credit).
            // colsum folded + atomically flushed per step -> only 4 live regs.
            float colsum[4] = {0.f, 0.f, 0.f, 0.f};
            #pragma unroll
            for (int mt = 0; mt < 2; ++mt)
                #pragma unroll
                for (int nt = 0; nt < 4; ++nt)
                    #pragma unroll
                    for (int r = 0; r < 4; ++r) {
                        const float e = __builtin_amdgcn_exp2f(acc[mt][nt][r]);
                        rowsum[mt][r] += e;
                        colsum[nt] += e;
                    }
            #pragma unroll
            for (int nt = 0; nt < 4; ++nt) {
                float s = colsum[nt];
                s += __shfl_xor(s, 16, 64);
                s += __shfl_xor(s, 32, 64);
                if (q == 0)
                    atomicAdd(&denom[colb + nt * 16 + l16], s);
            }
        }
    }

    // ---- row-sum reduction: across the 16 lanes holding the same row ----
    #pragma unroll
    for (int mt = 0; mt < 2; ++mt)
        #pragma unroll
        for (int r = 0; r < 4; ++r) {
            float s = rowsum[mt][r];
            s += __shfl_xor(s, 1, 64);
            s += __shfl_xor(s, 2, 64);
            s += __shfl_xor(s, 4, 64);
            s += __shfl_xor(s, 8, 64);
            rowsum[mt][r] = s;
        }
    if (l16 == 0) {
        #pragma unroll
        for (int mt = 0; mt < 2; ++mt)
            #pragma unroll
            for (int r = 0; r < 4; ++r) {
                const int grow = rowb + mt * 16 + q * 4 + r;
                atomicAdd(&denom[grow], rowsum[mt][r]);
            }
    }
}

__global__ __launch_bounds__(1024) void k_finish(
    const float* __restrict__ denom, const float* __restrict__ pos,
    float* __restrict__ out)
{
    __shared__ float red[16];
    const int t = threadIdx.x;
    const int lane = t & 63, wv = t >> 6;
    float s = 0.0f;
    for (int i = t; i < NROWS; i += 1024) s += __logf(denom[i]);
    float p = 0.0f;
    for (int i = t; i < N_PAIRS; i += 1024) p += pos[i];
    float v = s - 4.0f * p;   // sum_i pos_i/T over 2N rows = 4 * sum_p cos_p
    #pragma unroll
    for (int off = 1; off < 64; off <<= 1) v += __shfl_xor(v, off, 64);
    if (lane == 0) red[wv] = v;
    __syncthreads();
    if (wv == 0) {
        float x = (lane < 16) ? red[lane] : 0.0f;
        #pragma unroll
        for (int off = 1; off < 16; off <<= 1) x += __shfl_xor(x, off, 64);
        if (lane == 0) out[0] = x / (float)NROWS;
    }
}

extern "C" void kernel_launch(void* const* d_in, const int* in_sizes, int n_in,
                              void* d_out, int out_size, void* d_ws, size_t ws_size,
                              hipStream_t stream) {
    const float* z1 = (const float*)d_in[0];
    const float* z2 = (const float*)d_in[1];
    float* out = (float*)d_out;

    char* ws = (char*)d_ws;
    __hip_bfloat16* pack = (__hip_bfloat16*)ws;                // 2 MB
    float* denom = (float*)(ws + (size_t)NROWS * ZDIM * 2);    // 32 KB
    float* pos   = denom + NROWS;                              // 16 KB

    k_normalize<<<N_PAIRS / 4, 256, 0, stream>>>(z1, z2, pack, pos, denom);
    k_simsum<<<NBLK, 256, 0, stream>>>(pack, denom);
    k_finish<<<1, 1024, 0, stream>>>(denom, pos, out);
}

// Round 7
// 83.396 us; speedup vs baseline: 1.1388x; 1.0871x over previous
//
#include <hip/hip_runtime.h>
#include <hip/hip_bf16.h>

// NT-Xent loss, N=4096, Z=128, T=0.5.
//
// Round 4: scratch matrix in MFMA-FRAGMENT ORDER -> every A/B fragment load
// is a coalesced global_load_dwordx4 (1 KB/wave-load).
//   pack[(G*4 + ks)*64 + q*16 + n] (16B granules) = rows G*16+n,
//   k in [ks*32+q*8, +8).
// Rounds 5/6: symmetry halved FLOPs but regressed -- small (2-step) blocks
// are latency-dominated; the kernel is fragment-load-BW bound, not MFMA
// bound. Reverted.
// Round 7: full matrix, but 64-ROW WAVES (afrag[4][4]): each B-frag feeds
// 4 MFMAs instead of 2 -> L1 fragment traffic per CU halves (2.2->1.15 MB).
// 32-col half-steps (acc[4][2]) with B double-buffered in registers and
// next-step prefetch. Grid 512 blocks = 2/CU = 8 waves/CU (grid-limited),
// so up to 256 VGPR/wave are free: ~190 used, no spill.
//
//  k_normalize: row-normalize (fp32), quantize bf16 scaled by
//               QS = sqrt(2*log2(e)) (folds 1/T=2 and exp->exp2), write in
//               fragment order; exact fp32 pair-cosines pos[4096]; zero denom.
//  k_simsum:    denom[i] = sum_{j!=i} exp(2*sim_ij), full matrix.
//  k_finish:    out = (sum_i log denom_i - 4 * sum_p pos_p) / 8192

#define N_PAIRS 4096
#define ZDIM    128
#define NROWS   8192
#define QS 1.6986437717f   // sqrt(2 * log2(e))

typedef __bf16 bf16x8 __attribute__((ext_vector_type(8)));
typedef float  floatx4 __attribute__((ext_vector_type(4)));

__global__ __launch_bounds__(256) void k_normalize(
    const float* __restrict__ z1, const float* __restrict__ z2,
    __hip_bfloat16* __restrict__ pack, float* __restrict__ pos,
    float* __restrict__ denom)
{
    const int zi = blockIdx.x * 256 + threadIdx.x;   // grid 1024 blocks; 32 zero denom
    if (zi < NROWS) denom[zi] = 0.0f;

    const int w = threadIdx.x >> 6;
    const int lane = threadIdx.x & 63;
    const int p = blockIdx.x * 4 + w;            // pair index, < 4096
    const float2 a = ((const float2*)(z1 + (size_t)p * ZDIM))[lane];
    const float2 b = ((const float2*)(z2 + (size_t)p * ZDIM))[lane];
    float s1 = a.x * a.x + a.y * a.y;
    float s2 = b.x * b.x + b.y * b.y;
    float d  = a.x * b.x + a.y * b.y;
    #pragma unroll
    for (int off = 1; off < 64; off <<= 1) {
        s1 += __shfl_xor(s1, off, 64);
        s2 += __shfl_xor(s2, off, 64);
        d  += __shfl_xor(d,  off, 64);
    }
    const float n1 = fmaxf(sqrtf(s1), 1e-8f);
    const float n2 = fmaxf(sqrtf(s2), 1e-8f);
    const float i1 = 1.0f / n1, i2 = 1.0f / n2;
    const float q1 = i1 * QS, q2 = i2 * QS;
    float2 na; na.x = a.x * q1; na.y = a.y * q1;
    float2 nb; nb.x = b.x * q2; nb.y = b.y * q2;

    // lane holds elements e0=2*lane, e0+1 of its row:
    //   ks = lane>>4 ; q = (lane>>2)&3 ; j = (lane&3)*2
    // pack elem idx for row r: ((r>>4)*4 + ks)*512 + q*128 + (r&15)*8 + j
    const int ks = lane >> 4;
    const int qq = (lane >> 2) & 3;
    const int jj = (lane & 3) * 2;
    const int r1 = p, r2 = p + N_PAIRS;
    const size_t i1e = ((size_t)((r1 >> 4) * 4 + ks)) * 512 + qq * 128 + (r1 & 15) * 8 + jj;
    const size_t i2e = ((size_t)((r2 >> 4) * 4 + ks)) * 512 + qq * 128 + (r2 & 15) * 8 + jj;
    *(__hip_bfloat162*)(pack + i1e) = __float22bfloat162_rn(na);
    *(__hip_bfloat162*)(pack + i2e) = __float22bfloat162_rn(nb);
    if (lane == 0) pos[p] = d * i1 * i2;
}

// Block: 256 thr = 4 waves stacked vertically; wave w owns 64 rows
// [rt*256 + w*64, +64). Block tile 256 rows x 512 cols, swept in 16
// half-steps of 32 cols. Grid = 32 row-tiles x 16 col-slabs = 512 blocks
// = 2 blocks/CU, all co-resident in one dispatch round.
__global__ __launch_bounds__(256) void k_simsum(
    const __hip_bfloat16* __restrict__ pack, float* __restrict__ denom)
{
    const int tid  = threadIdx.x;
    const int lane = tid & 63;
    const int w    = tid >> 6;
    const int rt   = blockIdx.x >> 4;   // row tile [0,32)
    const int cs   = blockIdx.x & 15;   // col slab [0,16)
    const int q    = lane >> 4;         // quad 0..3
    const int l16  = lane & 15;

    // ---- persistent A fragments: wave's 64 rows x full K=128 (64 VGPRs) ----
    const int rowb = rt * 256 + w * 64;
    const __hip_bfloat16* Abase =
        pack + ((size_t)(rowb >> 4) * 4) * 512 + lane * 8;
    bf16x8 afrag[4][4];                  // [mt][ks]
    #pragma unroll
    for (int mt = 0; mt < 4; ++mt)
        #pragma unroll
        for (int ks = 0; ks < 4; ++ks)
            afrag[mt][ks] = *(const bf16x8*)(Abase + mt * 2048 + ks * 512);

    float rowsum[4][4];                  // [mt][r], persists over all steps
    #pragma unroll
    for (int mt = 0; mt < 4; ++mt)
        #pragma unroll
        for (int r = 0; r < 4; ++r) rowsum[mt][r] = 0.0f;

    // B fragment base for this col slab; per half-step hs the 32-col group
    // advances by 2 granule-groups = 4096 elements; nt*16 cols = 2048.
    const __hip_bfloat16* Bcol0 =
        pack + ((size_t)((cs * 512) >> 4) * 4) * 512 + lane * 8;

    auto loadB = [&](bf16x8 (&buf)[4][2], int hs) {
        const __hip_bfloat16* bp = Bcol0 + (size_t)hs * 4096;
        #pragma unroll
        for (int ks = 0; ks < 4; ++ks)      // ks-major: first MFMA waits least
            #pragma unroll
            for (int nt = 0; nt < 2; ++nt)
                buf[ks][nt] = *(const bf16x8*)(bp + nt * 2048 + ks * 512);
    };

    auto compute = [&](bf16x8 (&buf)[4][2], int hs) {
        floatx4 acc[4][2];
        #pragma unroll
        for (int mt = 0; mt < 4; ++mt)
            #pragma unroll
            for (int nt = 0; nt < 2; ++nt) {
                acc[mt][nt].x = 0.f; acc[mt][nt].y = 0.f;
                acc[mt][nt].z = 0.f; acc[mt][nt].w = 0.f;
            }
        #pragma unroll
        for (int ks = 0; ks < 4; ++ks)
            #pragma unroll
            for (int mt = 0; mt < 4; ++mt)
                #pragma unroll
                for (int nt = 0; nt < 2; ++nt)
                    acc[mt][nt] = __builtin_amdgcn_mfma_f32_16x16x32_bf16(
                        afrag[mt][ks], buf[ks][nt], acc[mt][nt], 0, 0, 0);
        // fused epilogue. C/D layout: col = l16, row = q*4 + r (m89/m91).
        const int colb = cs * 512 + hs * 32;
        #pragma unroll
        for (int mt = 0; mt < 4; ++mt) {
            const int rowtb = rowb + mt * 16;
            #pragma unroll
            for (int nt = 0; nt < 2; ++nt) {
                const int coltb = colb + nt * 16;
                if (rowtb == coltb) {        // wave-uniform: diagonal tile
                    #pragma unroll
                    for (int r = 0; r < 4; ++r) {
                        const float e = __builtin_amdgcn_exp2f(acc[mt][nt][r]);
                        rowsum[mt][r] += (l16 == q * 4 + r) ? 0.0f : e;
                    }
                } else {
                    #pragma unroll
                    for (int r = 0; r < 4; ++r)
                        rowsum[mt][r] += __builtin_amdgcn_exp2f(acc[mt][nt][r]);
                }
            }
        }
    };

    // ---- main sweep: 16 half-steps, register-double-buffered B ----
    bf16x8 bufA[4][2], bufB[4][2];
    loadB(bufA, 0);
    for (int hs = 0; hs < 16; hs += 2) {
        loadB(bufB, hs + 1);
        compute(bufA, hs);
        loadB(bufA, (hs + 2) & 15);    // wrap on last iter: valid mem, unused
        compute(bufB, hs + 1);
    }

    // ---- row-sum reduction: across the 16 lanes holding the same row ----
    #pragma unroll
    for (int mt = 0; mt < 4; ++mt)
        #pragma unroll
        for (int r = 0; r < 4; ++r) {
            float s = rowsum[mt][r];
            s += __shfl_xor(s, 1, 64);
            s += __shfl_xor(s, 2, 64);
            s += __shfl_xor(s, 4, 64);
            s += __shfl_xor(s, 8, 64);
            rowsum[mt][r] = s;
        }
    if (l16 == 0) {
        #pragma unroll
        for (int mt = 0; mt < 4; ++mt)
            #pragma unroll
            for (int r = 0; r < 4; ++r) {
                const int grow = rowb + mt * 16 + q * 4 + r;
                atomicAdd(&denom[grow], rowsum[mt][r]);
            }
    }
}

__global__ __launch_bounds__(1024) void k_finish(
    const float* __restrict__ denom, const float* __restrict__ pos,
    float* __restrict__ out)
{
    __shared__ float red[16];
    const int t = threadIdx.x;
    const int lane = t & 63, wv = t >> 6;
    float s = 0.0f;
    for (int i = t; i < NROWS; i += 1024) s += __logf(denom[i]);
    float p = 0.0f;
    for (int i = t; i < N_PAIRS; i += 1024) p += pos[i];
    float v = s - 4.0f * p;   // sum_i pos_i/T over 2N rows = 4 * sum_p cos_p
    #pragma unroll
    for (int off = 1; off < 64; off <<= 1) v += __shfl_xor(v, off, 64);
    if (lane == 0) red[wv] = v;
    __syncthreads();
    if (wv == 0) {
        float x = (lane < 16) ? red[lane] : 0.0f;
        #pragma unroll
        for (int off = 1; off < 16; off <<= 1) x += __shfl_xor(x, off, 64);
        if (lane == 0) out[0] = x / (float)NROWS;
    }
}

extern "C" void kernel_launch(void* const* d_in, const int* in_sizes, int n_in,
                              void* d_out, int out_size, void* d_ws, size_t ws_size,
                              hipStream_t stream) {
    const float* z1 = (const float*)d_in[0];
    const float* z2 = (const float*)d_in[1];
    float* out = (float*)d_out;

    char* ws = (char*)d_ws;
    __hip_bfloat16* pack = (__hip_bfloat16*)ws;                // 2 MB
    float* denom = (float*)(ws + (size_t)NROWS * ZDIM * 2);    // 32 KB
    float* pos   = denom + NROWS;                              // 16 KB

    k_normalize<<<N_PAIRS / 4, 256, 0, stream>>>(z1, z2, pack, pos, denom);
    k_simsum<<<512, 256, 0, stream>>>(pack, denom);
    k_finish<<<1, 1024, 0, stream>>>(denom, pos, out);
}